// Round 17
// baseline (19.205 us; speedup 1.0000x reference)
//
#include <hip/hip_runtime.h>
#include <hip/hip_bf16.h>

// RDF with minimum-image PBC + Gaussian smearing, N=2048 atoms, 100 bins.
//
// Round-17: r16 handoff (validated: returning-exch publish + relaxed
// two-level tickets + single acquire + system-scope readback; absmax at
// the 0.0078 quantization floor), with TWO body changes:
//  1. 512 blocks x 512 threads (2 blocks/CU, 8 waves each) instead of
//     256 x 1024 (1 block/CU, 16 waves). r16's recalibration (acq_rel
//     tickets cost ~2us, not 13) pins the body at ~13.5us, invariant
//     since r4; issue-count says ~4-5us. The gap: with ONE block/CU,
//     every __syncthreads (x6: prologue/merge/conv/publish) drains all
//     16 waves with nothing else resident; epilogue phases use <=400 of
//     1024 threads while the rest idle at barriers. Two blocks/CU let
//     one block's barrier phases overlap the other's main loop.
//     NCOPY=2 keeps 4 waves/copy (same LDS-atomic contention as r13);
//     LDS ~18KB/block -> both blocks fit with slack.
//  2. minimum-image wrap via d -= c*rintf(d*inv_c) (3 VALU/axis vs ~7).
//     Semantics: differs from the reference's shift rule only at the
//     exact half-box boundary d == +-0.5c, where the two wrapped values
//     have EQUAL MAGNITUDE -> dsq (all the op consumes) is identical.
//
// Rest as r13/r16: block owns 4 rows of the cyclic upper-triangle
// enumeration (j=(i+1+t) mod N, t in [0,1024), two 512-wide passes; one
// predicate dedups the d==N/2 diagonal; x2 pair weight cancels in count
// normalization). i wave-uniform -> scalar i-loads; j-loads coalesced,
// L1-resident (xyz=24KB). ONE u32 LDS atomic per pair into a FINE
// distance histogram (17 sub-bins/bin, 2 private copies; integer counts
// -> exact, order-independent). Epilogue merges copies + convolves with
// a 103-tap Gaussian (stride 17 coprime with 32 banks -> conflict-free).
// Pairs with dist < 8 bin-units (~250 device-wide) take an exact f32
// direct-smear path into bins 0..11 (tiny shell volumes amplify
// quantization error there). Winner reduces in fixed order ->
// deterministic; d_out = [count(100) | bins(101) | rdf(100)].
// No zeroing anywhere: partials rows fully overwritten (returning exch);
// tickets use the modulo trick (divisors of 2^32, exact increment counts
// per call -> one winner from any poison value). Single graph node.

#define N_ATOMS 2048
#define HALF    1024
#define NBINS   100
#define S_FINE  17          // fine sub-bins per coarse bin (coprime with 32)
#define FBINS   1744        // > 102.5 * 17 = 1742.5
#define NCOPY   2           // private fine-histogram copies (4 waves each)
#define TAPS    103         // 2*3*17 + 1  (window +-3 bin widths)
#define NDIR    12          // exact direct-path coarse bins 0..11
#define TLOW    8.0f        // bin-units: below this, take the exact path
#define NBLOCKS 512         // power of 2: modulo tickets need divisors of 2^32
#define NTHREADS 512
#define ROWS_PB 4           // N_ATOMS / NBLOCKS
#define PADB    112         // padded row stride for publish slots
#define NSUB    16          // sub-tickets; NBLOCKS/NSUB = 32 arrivals each
#define TSTRIDE 64          // words between ticket slots (256B apart)

__global__ __launch_bounds__(512) void rdf_fused(
    const float* __restrict__ xyz,
    const float* __restrict__ cell,
    const float* __restrict__ offsets,
    const float* __restrict__ bins,
    float* __restrict__ out,
    float* __restrict__ partials,   // [NBLOCKS][PADB], exch-overwritten
    unsigned* __restrict__ tickets) // NSUB subs + 1 master, never reset
{
    __shared__ unsigned fine[NCOPY][FBINS];  // private fine histograms (u32)
    __shared__ float wtab[TAPS];             // Gaussian taps
    __shared__ float conv[NBINS][4];         // conv partials / tail reduce
    __shared__ float cd[16];                 // exact direct-path coarse bins
    __shared__ float ssum[2];
    __shared__ unsigned stick;

    const int tid = threadIdx.x;
    const int bid = blockIdx.x;

    for (int a = tid; a < NCOPY * FBINS; a += NTHREADS)
        (&fine[0][0])[a] = 0u;
    if (tid < 16)   cd[tid] = 0.0f;
    if (tid < TAPS) {
        const float u = ((float)tid - 50.5f) * (1.0f / (float)S_FINE);
        wtab[tid] = __expf(-0.5f * u * u);
    }
    __syncthreads();

    const float cx = cell[0], cy = cell[1], cz = cell[2];
    const float icx = 1.0f / cx, icy = 1.0f / cy, icz = 1.0f / cz;

    const float width = offsets[1] - offsets[0];   // 7.5/99
    const float invw  = 1.0f / width;
    // beyond 102.5 bin-units no bin k<=99 lies within the +-3w window
    const float cutd   = 102.5f * width;           // 7.765 < CUTOFF_B = 8.0
    const float cut2   = cutd * cutd;

    unsigned* const myfine = fine[tid >> 8];       // 4 waves per copy

    // ---- main loop: 4 rows per block, two 512-wide passes per row ----
    const int row0 = bid << 2;
    #pragma unroll
    for (int r = 0; r < ROWS_PB; ++r) {
        const int i = row0 + r;                    // wave-uniform
        const float xi = xyz[3 * i + 0];           // scalar loads
        const float yi = xyz[3 * i + 1];
        const float zi = xyz[3 * i + 2];
        #pragma unroll
        for (int p = 0; p < HALF / NTHREADS; ++p) {
            const int th = tid + p * NTHREADS;
            if (th == HALF - 1 && i >= HALF) continue; // dedup N/2 diagonal
            const int j = (i + 1 + th) & (N_ATOMS - 1);

            float dx = xyz[3 * j + 0] - xi;        // coalesced, L1-resident
            float dy = xyz[3 * j + 1] - yi;
            float dz = xyz[3 * j + 2] - zi;
            // minimum-image wrap: dsq-identical to the reference rule
            // (half-boundary cases differ only in sign of the wrap)
            dx -= cx * rintf(dx * icx);
            dy -= cy * rintf(dy * icy);
            dz -= cz * rintf(dz * icz);

            const float dsq = dx * dx + dy * dy + dz * dz;
            if (dsq < cut2 && dsq != 0.0f) {
                const float tu = sqrtf(dsq) * invw;    // dist in bin units
                if (tu >= TLOW) {
                    // ONE native u32 LDS atomic/pair; scatter over 1744
                    atomicAdd(&myfine[(int)(tu * (float)S_FINE)], 1u);
                } else {
                    // exact f32 path for low bins (~250 pairs device-wide)
                    int khi = (int)tu + 4; if (khi > NDIR - 1) khi = NDIR - 1;
                    for (int k = 0; k <= khi; ++k) {
                        const float e = tu - (float)k;
                        atomicAdd(&cd[k], __expf(-0.5f * e * e));
                    }
                }
            }
        }
    }

    __syncthreads();

    // merge copy 1 into copy 0 (stride-1, conflict-free, int adds)
    for (int a = tid; a < FBINS; a += NTHREADS)
        fine[0][a] += fine[1][a];
    __syncthreads();

    // coarse[k] = sum_d wtab[d+51] * fine[17k+d], d in [-51,51]
    // 400 threads: k = t>>2, chunk c = t&3 (26/26/26/25 taps); stride-17
    // fine reads are bank-conflict free (gcd(17,32)=1)
    if (tid < 400) {
        const int k = tid >> 2;
        const int c = tid & 3;
        const int m0 = c * 26;
        const int mcnt = (c == 3) ? 25 : 26;
        float s = 0.0f;
        for (int mm = 0; mm < mcnt; ++mm) {
            const int m = m0 + mm;
            const int f = S_FINE * k + m - 51;     // max 17*99+51 = 1734
            if (f >= 0) s += wtab[m] * (float)fine[0][f];  // exact: < 2^24
        }
        conv[k][c] = s;
    }
    __syncthreads();

    // ---- publish: RETURNING atomicExch into per-block-unique slots.
    // Returning form (sc0) completes only after the IF round-trip, so
    // after the barrier all 100 swaps are PERFORMED at the coherence
    // point before thread 0's ticket RMW (r16-validated).
    if (tid < NBINS) {
        float raw = conv[tid][0] + conv[tid][1] + conv[tid][2] + conv[tid][3];
        if (tid < NDIR) raw += cd[tid];
        float old = atomicExch(&partials[bid * PADB + tid], raw);
        asm volatile("" :: "v"(old));   // keep the return value live
    }

    __syncthreads();
    if (tid == 0) {
        unsigned last = 0u;
        const unsigned so = __hip_atomic_fetch_add(
            &tickets[(bid & (NSUB - 1)) * TSTRIDE], 1u,
            __ATOMIC_RELAXED, __HIP_MEMORY_SCOPE_AGENT);
        if ((so & (NBLOCKS / NSUB - 1)) == (NBLOCKS / NSUB - 1)) {
            // sub-group's last arrival; its RMW completed before this one
            const unsigned mo = __hip_atomic_fetch_add(
                &tickets[NSUB * TSTRIDE], 1u,
                __ATOMIC_RELAXED, __HIP_MEMORY_SCOPE_AGENT);
            last = ((mo & (NSUB - 1)) == (NSUB - 1)) ? 1u : 0u;
        }
        if (last) {
            // ONE acquire (single cache invalidate) for the whole handoff
            __hip_atomic_fetch_add(&tickets[NSUB * TSTRIDE], 0u,
                                   __ATOMIC_ACQUIRE, __HIP_MEMORY_SCOPE_AGENT);
        }
        stick = last;
    }
    __syncthreads();
    if (!stick) return;

    // ---- winner: readback via SYSTEM-scope relaxed loads (bypass
    // L1&L2, read at IF where the swaps landed). thread t: bin b=t&127,
    // chunk c=t>>7 (0..3); sums 128 blocks each, fixed order.
    {
        const int b = tid & 127;
        const int c = tid >> 7;
        if (b < NBINS) {
            float s = 0.0f;
            #pragma unroll 8
            for (int q = 0; q < NBLOCKS / 4; ++q) {
                const int blk = c * (NBLOCKS / 4) + q;
                s += __hip_atomic_load(&partials[blk * PADB + b],
                                       __ATOMIC_RELAXED,
                                       __HIP_MEMORY_SCOPE_SYSTEM);
            }
            conv[b][c] = s;
        }
    }
    __syncthreads();

    float raw = 0.0f;
    if (tid < NBINS) {
        #pragma unroll
        for (int c = 0; c < 4; ++c) raw += conv[tid][c];
    }
    if (tid < 128) {
        float v = raw;
        #pragma unroll
        for (int o = 32; o > 0; o >>= 1) v += __shfl_down(v, o);
        if ((tid & 63) == 0) ssum[tid >> 6] = v;
    }
    __syncthreads();
    const float S = ssum[0] + ssum[1];

    if (tid < NBINS) {
        const float cnt = raw / S;
        out[tid] = cnt;                                // count
        const float b0 = bins[tid], b1 = bins[tid + 1];
        const float R  = bins[NBINS];                  // R_END = 7.5
        // rdf = cnt / (vol_bin / V) = cnt * R^3 / (b1^3 - b0^3)  (4pi/3 cancels)
        out[201 + tid] = cnt * (R * R * R) / (b1 * b1 * b1 - b0 * b0 * b0);
    }
    if (tid < NBINS + 1) {
        out[100 + tid] = bins[tid];                    // bins passthrough
    }
}

extern "C" void kernel_launch(void* const* d_in, const int* in_sizes, int n_in,
                              void* d_out, int out_size, void* d_ws, size_t ws_size,
                              hipStream_t stream) {
    const float* xyz     = (const float*)d_in[0];
    const float* cell    = (const float*)d_in[1];
    const float* bins    = (const float*)d_in[2];
    const float* offsets = (const float*)d_in[3];
    float* out = (float*)d_out;

    float*    partials = (float*)d_ws;   // NBLOCKS*PADB floats, exch-overwritten
    unsigned* tickets  = (unsigned*)((char*)d_ws +
                                     (size_t)NBLOCKS * PADB * sizeof(float));

    // single graph node: no memset, no second kernel
    rdf_fused<<<NBLOCKS, NTHREADS, 0, stream>>>(xyz, cell, offsets, bins, out,
                                                partials, tickets);
}